// Round 5
// baseline (826.192 us; speedup 1.0000x reference)
//
#include <hip/hip_runtime.h>
#include <hip/hip_bf16.h>
#include <stdint.h>

#define B_ 4
#define S_ 2048
#define H_ 1024
#define I_ 4096
#define E_ 8
#define CAP 640
#define NTOK (B_*S_)            // 8192
#define NBE  (B_*E_)            // 32

typedef _Float16 f16;
typedef f16 f16x8 __attribute__((ext_vector_type(8)));
typedef float f32x4 __attribute__((ext_vector_type(4)));

// workspace layout (bytes)
#define OFF_LOGITS 0u                          // 65536 f32
#define OFF_TOPKI  (256u*1024u)                // 20480 int
#define OFF_TOPKW  (OFF_TOPKI + 128u*1024u)    // 20480 f32
#define OFF_COUNTS (OFF_TOPKW + 128u*1024u)    // 8192 f32
#define OFF_SCAL   (OFF_COUNTS + 64u*1024u)    // 16 f32
#define OFF_XH     (1u<<20)                    // 8192*1024 f16   (16.8 MB)
#define OFF_WT     (18u<<20)                   // 8*4096*1024 f16 (67.1 MB) — w1t then w2t (reused)
#define OFF_MID    (86u<<20)                   // 20480*4096 f16  (167.8 MB) → high-water ~254 MB

__device__ __forceinline__ void gl_lds16(const void* g, void* l) {
    __builtin_amdgcn_global_load_lds(
        (const __attribute__((address_space(1))) uint32_t*)g,
        (__attribute__((address_space(3))) uint32_t*)l, 16, 0, 0);
}

// ---------------------------------------------------------------- router ----
// NOTE: summation order is frozen — top-k selection depends on exact fp32
// logit ordering near capacity boundaries. Do not restructure this reduce.
__global__ void k_router(const float* __restrict__ x, const float* __restrict__ rw,
                         float* __restrict__ logits, float* __restrict__ scal) {
    __shared__ float rwt[E_ * H_];
    __shared__ float part[4][9];
    int tid = threadIdx.x;
    for (int i = tid; i < E_ * H_; i += 256) {
        int h = i >> 3, e = i & 7;
        rwt[e * H_ + h] = rw[i];
    }
    __syncthreads();
    int w = tid >> 6, lane = tid & 63;
    int t = blockIdx.x * 4 + w;
    const float* xr = x + (size_t)t * H_;
    float acc[E_];
#pragma unroll
    for (int e = 0; e < E_; ++e) acc[e] = 0.f;
    for (int it = 0; it < H_ / 64; ++it) {
        int h = lane + it * 64;
        float xv = xr[h];
#pragma unroll
        for (int e = 0; e < E_; ++e) acc[e] += xv * rwt[e * H_ + h];
    }
#pragma unroll
    for (int off = 32; off > 0; off >>= 1)
#pragma unroll
        for (int e = 0; e < E_; ++e) acc[e] += __shfl_down(acc[e], off);
    if (lane == 0) {
        int b = t >> 11, s = t & 2047;
        float m = acc[0];
#pragma unroll
        for (int e = 1; e < E_; ++e) m = fmaxf(m, acc[e]);
        float z = 0.f, ps = 0.f;
        float p[E_];
#pragma unroll
        for (int e = 0; e < E_; ++e) {
            logits[(size_t)((b << 3) + e) * S_ + s] = acc[e];
            z += acc[e] * acc[e];
            p[e] = expf(acc[e] - m);
            ps += p[e];
        }
        part[w][0] = z;
#pragma unroll
        for (int e = 0; e < E_; ++e) part[w][1 + e] = p[e] / ps;
    }
    __syncthreads();
    if (tid < 9) {
        float v = part[0][tid] + part[1][tid] + part[2][tid] + part[3][tid];
        atomicAdd(&scal[tid], v);
    }
}

// ----------------------------------------------------------------- top-k ----
__global__ void __launch_bounds__(1024) k_topk(const float* __restrict__ logits,
                                               int* __restrict__ tki,
                                               float* __restrict__ tkw,
                                               float* __restrict__ counts) {
    int be = blockIdx.x;
    const float* row = logits + (size_t)be * S_;
    __shared__ unsigned long long keys[S_];
    __shared__ float wpart[16];
    __shared__ float stot;
    int tid = threadIdx.x;
    for (int i = tid; i < S_; i += 1024) {
        unsigned u = __float_as_uint(row[i]);
        u = (u & 0x80000000u) ? ~u : (u | 0x80000000u);
        keys[i] = ((unsigned long long)u << 32) | (unsigned)(~i);
    }
    __syncthreads();
    for (int k = 2; k <= S_; k <<= 1) {
        for (int j = k >> 1; j > 0; j >>= 1) {
#pragma unroll
            for (int base = 0; base < S_; base += 1024) {
                int i = base + tid;
                int ixj = i ^ j;
                if (ixj > i) {
                    unsigned long long a = keys[i], b = keys[ixj];
                    bool up = ((i & k) == 0);
                    bool sw = up ? (a < b) : (a > b);
                    if (sw) { keys[i] = b; keys[ixj] = a; }
                }
            }
            __syncthreads();
        }
    }
    int idx0 = (int)(~(unsigned)(keys[0] & 0xFFFFFFFFu));
    float vmax = row[idx0];
    int myidx = 0; float ex = 0.f;
    if (tid < CAP) {
        myidx = (int)(~(unsigned)(keys[tid] & 0xFFFFFFFFu));
        ex = expf(row[myidx] - vmax);
    }
    float v = ex;
#pragma unroll
    for (int off = 32; off > 0; off >>= 1) v += __shfl_down(v, off);
    if ((tid & 63) == 0) wpart[tid >> 6] = v;
    __syncthreads();
    if (tid == 0) {
        float s = 0.f;
#pragma unroll
        for (int i = 0; i < 16; ++i) s += wpart[i];
        stot = s;
    }
    __syncthreads();
    if (tid < CAP) {
        tki[be * CAP + tid] = myidx;
        tkw[be * CAP + tid] = ex / stot;
        atomicAdd(&counts[(be >> 3) * S_ + myidx], 1.0f);
    }
}

// ------------------------------------------------------------ conversions ---
__global__ void k_cvt_x(const float* __restrict__ in, f16* __restrict__ out) {
    size_t i = ((size_t)blockIdx.x * 256 + threadIdx.x) << 3;
    float4 a = *(const float4*)(in + i);
    float4 b = *(const float4*)(in + i + 4);
    f16x8 o = { (f16)a.x, (f16)a.y, (f16)a.z, (f16)a.w,
                (f16)b.x, (f16)b.y, (f16)b.z, (f16)b.w };
    *(f16x8*)(out + i) = o;
}

// in: [E][R][C] f32 → out: [E][C][R] f16
template<int R, int C>
__global__ void __launch_bounds__(256) k_transpose(const float* __restrict__ in,
                                                   f16* __restrict__ out) {
    __shared__ f16 t[64][68];
    int e = blockIdx.z;
    const float* ine = in + (size_t)e * R * C;
    f16* oute = out + (size_t)e * R * C;
    int c0 = blockIdx.x << 6, r0 = blockIdx.y << 6;
    int tx = threadIdx.x & 15, ty = threadIdx.x >> 4;
#pragma unroll
    for (int p = 0; p < 4; ++p) {
        int r = ty + p * 16;
        float4 v = *(const float4*)(ine + (size_t)(r0 + r) * C + c0 + tx * 4);
        t[tx * 4 + 0][r] = (f16)v.x;
        t[tx * 4 + 1][r] = (f16)v.y;
        t[tx * 4 + 2][r] = (f16)v.z;
        t[tx * 4 + 3][r] = (f16)v.w;
    }
    __syncthreads();
#pragma unroll
    for (int p = 0; p < 4; ++p) {
        int c = ty + p * 16;
        *(ushort4*)(oute + (size_t)(c0 + c) * R + r0 + tx * 4) =
            *(const ushort4*)&t[c][tx * 4];
    }
}

// ============================ GEMM core geometry =============================
// 512 thr = 8 waves (wm=w>>2 in {0,1}, wn=w&3). Tile 256x256, BK=64.
// Expert-major rows: expert e owns rows ge in [0,2560); b=ge/640, c=ge%640.
// LDS: A/B double-buffered [2][256][64] f16 = 128 KB. 8-slot XOR swizzle:
// 16B chunk s of row r lives at slot s ^ (r&7)  (involution; staged via
// pre-swizzled global source, read with same XOR → full-BW ds_read_b128).
// Per K-tile: 4 phases {ds_read frags; 2 gl_lds; setprio(1); 16 MFMA;
// setprio(0)}; all 8 next-tile gl_lds issued in phases 0-1 →
// ~2000cy cover; one vmcnt(0)+s_barrier per K-tile (512 MFMA amortize it).

#define MFMA4(MI, A) \
    acc[MI][0] = __builtin_amdgcn_mfma_f32_16x16x32_f16(A, bf0, acc[MI][0], 0, 0, 0); \
    acc[MI][1] = __builtin_amdgcn_mfma_f32_16x16x32_f16(A, bf1, acc[MI][1], 0, 0, 0); \
    acc[MI][2] = __builtin_amdgcn_mfma_f32_16x16x32_f16(A, bf2, acc[MI][2], 0, 0, 0); \
    acc[MI][3] = __builtin_amdgcn_mfma_f32_16x16x32_f16(A, bf3, acc[MI][3], 0, 0, 0);

// ---------------------------------------------------------- GEMM1 (+SiLU) ---
__global__ void __launch_bounds__(512, 2) k_gemm1(const f16* __restrict__ xh,
                                                  const f16* __restrict__ w1t,
                                                  const int* __restrict__ tki,
                                                  f16* __restrict__ mid) {
    __shared__ f16 Ab[2 * 256 * 64];   // 64 KB
    __shared__ f16 Bb[2 * 256 * 64];   // 64 KB
    int bid = blockIdx.x;
    int orig = (bid & 7) * 160 + (bid >> 3);   // XCD-chunked swizzle (1280%8==0)
    int ct = orig & 15;
    int g = orig >> 4;
    int mt = g % 10;
    int e = g / 10;
    int n0 = ct << 8;
    const f16* w1e = w1t + ((size_t)e << 22);
    int tid = threadIdx.x;
    int w = tid >> 6, l = tid & 63;
    int wm = w >> 2, wn = w & 3;

    // ---- staging setup: 4 A + 4 B gl_lds per thread per K-tile
    int lrow = l >> 3;                 // 0..7
    int chunk = (l & 7) ^ lrow;        // inverse swizzle on global source
    const f16* aSrc[4];
    const f16* bSrc[4];
    int aDst[4], bDst[4];
#pragma unroll
    for (int i = 0; i < 4; ++i) {
        int r = (w << 5) + (i << 3) + lrow;          // 0..255
        int ge = mt * 256 + r;
        int bb = ge / 640;
        int cc = ge - bb * 640;
        int tok = tki[(((bb << 3) + e) * 640) + cc];
        aSrc[i] = xh + ((size_t)((bb << 11) + tok) << 10) + (chunk << 3);
        bSrc[i] = w1e + ((size_t)(n0 + r) << 10) + (chunk << 3);
        aDst[i] = ((w << 5) + (i << 3)) << 6;        // wave-uniform
        bDst[i] = aDst[i];
    }

    // prologue: stage K-tile 0 into buffer 0
#pragma unroll
    for (int i = 0; i < 4; ++i) {
        gl_lds16(aSrc[i], Ab + aDst[i]);
        gl_lds16(bSrc[i], Bb + bDst[i]);
    }
    __syncthreads();

    int fr = l & 15, hi = l >> 4;
    int s0 = ((hi ^ (fr & 7)) << 3);
    int aBase = ((wm << 7) + fr) << 6;
    int bBase = ((wn << 6) + fr) << 6;
    f32x4 acc[8][4];
#pragma unroll
    for (int mi = 0; mi < 8; ++mi)
#pragma unroll
        for (int ni = 0; ni < 4; ++ni) acc[mi][ni] = (f32x4){0.f, 0.f, 0.f, 0.f};

    for (int t = 0; t < 16; ++t) {
        const f16* Ac = Ab + ((t & 1) << 14);
        const f16* Bc = Bb + ((t & 1) << 14);
        f16* An = Ab + (((t & 1) ^ 1) << 14);
        f16* Bn = Bb + (((t & 1) ^ 1) << 14);
        int ko = ((t < 15) ? (t + 1) : 15) << 6;
        // phase 0: k-frag 0, m-half 0 (+ all B k0); stage A chunks 0,1
        f16x8 bf0 = *(const f16x8*)(Bc + bBase + s0);
        f16x8 bf1 = *(const f16x8*)(Bc + bBase + 1024 + s0);
        f16x8 bf2 = *(const f16x8*)(Bc + bBase + 2048 + s0);
        f16x8 bf3 = *(const f16x8*)(Bc + bBase + 3072 + s0);
        f16x8 a0 = *(const f16x8*)(Ac + aBase + s0);
        f16x8 a1 = *(const f16x8*)(Ac + aBase + 1024 + s0);
        f16x8 a2 = *(const f16x8*)(Ac + aBase + 2048 + s0);
        f16x8 a3 = *(const f16x8*)(Ac + aBase + 3072 + s0);
        gl_lds16(aSrc[0] + ko, An + aDst[0]);
        gl_lds16(aSrc[1] + ko, An + aDst[1]);
        __builtin_amdgcn_s_setprio(1);
        MFMA4(0, a0) MFMA4(1, a1) MFMA4(2, a2) MFMA4(3, a3)
        __builtin_amdgcn_s_setprio(0);
        // phase 1: k0, m-half 1; stage A chunks 2,3
        a0 = *(const f16x8*)(Ac + aBase + 4096 + s0);
        a1 = *(const f16x8*)(Ac + aBase + 5120 + s0);
        a2 = *(const f16x8*)(Ac + aBase + 6144 + s0);
        a3 = *(const f16x8*)(Ac + aBase + 7168 + s0);
        gl_lds16(aSrc[2] + ko, An + aDst[2]);
        gl_lds16(aSrc[3] + ko, An + aDst[3]);
        __builtin_amdgcn_s_setprio(1);
        MFMA4(4, a0) MFMA4(5, a1) MFMA4(6, a2) MFMA4(7, a3)
        __builtin_amdgcn_s_setprio(0);
        // phase 2: k1, m-half 0 (+ all B k1); stage B chunks 0,1
        int s1 = s0 ^ 32;
        bf0 = *(const f16x8*)(Bc + bBase + s1);
        bf1 = *(const f16x8*)(Bc + bBase + 1024 + s1);
        bf2 = *(const f16x8*)(Bc + bBase + 2048 + s1);
        bf3 = *(const f16x8*)(Bc + bBase + 3072 + s1);
        a0 = *(const f16x8*)(Ac + aBase + s1);
        a1 = *(const f16x8*)(Ac + aBase + 1024 + s1);
        a2 = *(const f16x8*)(Ac + aBase + 2048 + s1);
        a3 = *(const f16x8*)(Ac + aBase + 3072 + s1);
        gl_lds16(bSrc[0] + ko, Bn + bDst[0]);
        gl_lds16(bSrc[1] + ko, Bn + bDst[1]);
        __builtin_amdgcn_s_setprio(1);
        MFMA4(0, a0) MFMA4(1, a1) MFMA4(2, a2) MFMA4(3, a3)
        __builtin_amdgcn_s_setprio(0);
        // phase 3: k1, m-half 1; stage B chunks 2,3
        a0 = *(const f16x8*)(Ac + aBase + 4096 + s1);
        a1 = *(const f16x8*)(Ac + aBase + 5120 + s1);
        a2 = *(const f16x8*)(Ac + aBase + 6144 + s1);
        a3 = *(const f16x8*)(Ac + aBase + 7168 + s1);
        gl_lds16(bSrc[2] + ko, Bn + bDst[2]);
        gl_lds16(bSrc[3] + ko, Bn + bDst[3]);
        __builtin_amdgcn_s_setprio(1);
        MFMA4(4, a0) MFMA4(5, a1) MFMA4(6, a2) MFMA4(7, a3)
        __builtin_amdgcn_s_setprio(0);
        asm volatile("s_waitcnt vmcnt(0)" ::: "memory");
        __builtin_amdgcn_s_barrier();
    }

    // epilogue: SiLU + f16 store to mid (expert-major row → flat [be][cap] row)
    int rq4 = hi << 2;
#pragma unroll
    for (int mi = 0; mi < 8; ++mi) {
        int row = (wm << 7) + mi * 16 + rq4;
#pragma unroll
        for (int q = 0; q < 4; ++q) {
            int ge = mt * 256 + row + q;
            int bb = ge / 640;
            int cc = ge - bb * 640;
            size_t flat = (size_t)(((bb << 3) + e) * 640 + cc);
            f16* mrow = mid + (flat << 12) + n0 + (wn << 6) + fr;
#pragma unroll
            for (int ni = 0; ni < 4; ++ni) {
                float v = acc[mi][ni][q];
                v = v / (1.f + expf(-v));
                mrow[ni * 16] = (f16)v;
            }
        }
    }
}

// ------------------------------------------- GEMM2 + weighted atomic scatter
// K split 4 ways (ks): partials combined via the existing f32 atomicAdd.
__global__ void __launch_bounds__(512, 2) k_gemm2(const f16* __restrict__ mid,
                                                  const f16* __restrict__ w2t,
                                                  const int* __restrict__ tki,
                                                  const float* __restrict__ tkw,
                                                  float* __restrict__ out) {
    __shared__ f16 Ab[2 * 256 * 64];
    __shared__ f16 Bb[2 * 256 * 64];
    __shared__ int   rowOffS[256];
    __shared__ float wtsS[256];
    int bid = blockIdx.x;
    int orig = (bid & 7) * 160 + (bid >> 3);
    int ct = orig & 3;
    int ks = (orig >> 2) & 3;
    int g = orig >> 4;
    int mt = g % 10;
    int e = g / 10;
    int n0 = ct << 8;
    const f16* w2e = w2t + ((size_t)e << 22);
    int tid = threadIdx.x;
    int w = tid >> 6, l = tid & 63;
    int wm = w >> 2, wn = w & 3;

    if (tid < 256) {
        int ge = mt * 256 + tid;
        int bb = ge / 640;
        int cc = ge - bb * 640;
        int flat = ((bb << 3) + e) * 640 + cc;
        int tok = tki[flat];
        rowOffS[tid] = ((bb << 11) + tok) << 10;   // (b*S + tok) * H
        wtsS[tid] = tkw[flat];
    }

    int lrow = l >> 3;
    int chunk = (l & 7) ^ lrow;
    const f16* aSrc[4];
    const f16* bSrc[4];
    int aDst[4], bDst[4];
#pragma unroll
    for (int i = 0; i < 4; ++i) {
        int r = (w << 5) + (i << 3) + lrow;
        int ge = mt * 256 + r;
        int bb = ge / 640;
        int cc = ge - bb * 640;
        size_t flat = (size_t)(((bb << 3) + e) * 640 + cc);
        aSrc[i] = mid + (flat << 12) + (ks << 10) + (chunk << 3);
        bSrc[i] = w2e + ((size_t)(n0 + r) << 12) + (ks << 10) + (chunk << 3);
        aDst[i] = ((w << 5) + (i << 3)) << 6;
        bDst[i] = aDst[i];
    }

#pragma unroll
    for (int i = 0; i < 4; ++i) {
        gl_lds16(aSrc[i], Ab + aDst[i]);
        gl_lds16(bSrc[i], Bb + bDst[i]);
    }
    __syncthreads();

    int fr = l & 15, hi = l >> 4;
    int s0 = ((hi ^ (fr & 7)) << 3);
    int aBase = ((wm << 7) + fr) << 6;
    int bBase = ((wn << 6) + fr) << 6;
    f32x4 acc[8][4];
#pragma unroll
    for (int mi = 0; mi < 8; ++mi)
#pragma unroll
        for (int ni = 0; ni < 4; ++ni) acc[mi][ni] = (f32x4){0.f, 0.f, 0.f, 0.f};

    for (int t = 0; t < 16; ++t) {
        const f16* Ac = Ab + ((t & 1) << 14);
        const f16* Bc = Bb + ((t & 1) << 14);
        f16* An = Ab + (((t & 1) ^ 1) << 14);
        f16* Bn = Bb + (((t & 1) ^ 1) << 14);
        int ko = ((t < 15) ? (t + 1) : 15) << 6;
        f16x8 bf0 = *(const f16x8*)(Bc + bBase + s0);
        f16x8 bf1 = *(const f16x8*)(Bc + bBase + 1024 + s0);
        f16x8 bf2 = *(const f16x8*)(Bc + bBase + 2048 + s0);
        f16x8 bf3 = *(const f16x8*)(Bc + bBase + 3072 + s0);
        f16x8 a0 = *(const f16x8*)(Ac + aBase + s0);
        f16x8 a1 = *(const f16x8*)(Ac + aBase + 1024 + s0);
        f16x8 a2 = *(const f16x8*)(Ac + aBase + 2048 + s0);
        f16x8 a3 = *(const f16x8*)(Ac + aBase + 3072 + s0);
        gl_lds16(aSrc[0] + ko, An + aDst[0]);
        gl_lds16(aSrc[1] + ko, An + aDst[1]);
        __builtin_amdgcn_s_setprio(1);
        MFMA4(0, a0) MFMA4(1, a1) MFMA4(2, a2) MFMA4(3, a3)
        __builtin_amdgcn_s_setprio(0);
        a0 = *(const f16x8*)(Ac + aBase + 4096 + s0);
        a1 = *(const f16x8*)(Ac + aBase + 5120 + s0);
        a2 = *(const f16x8*)(Ac + aBase + 6144 + s0);
        a3 = *(const f16x8*)(Ac + aBase + 7168 + s0);
        gl_lds16(aSrc[2] + ko, An + aDst[2]);
        gl_lds16(aSrc[3] + ko, An + aDst[3]);
        __builtin_amdgcn_s_setprio(1);
        MFMA4(4, a0) MFMA4(5, a1) MFMA4(6, a2) MFMA4(7, a3)
        __builtin_amdgcn_s_setprio(0);
        int s1 = s0 ^ 32;
        bf0 = *(const f16x8*)(Bc + bBase + s1);
        bf1 = *(const f16x8*)(Bc + bBase + 1024 + s1);
        bf2 = *(const f16x8*)(Bc + bBase + 2048 + s1);
        bf3 = *(const f16x8*)(Bc + bBase + 3072 + s1);
        a0 = *(const f16x8*)(Ac + aBase + s1);
        a1 = *(const f16x8*)(Ac + aBase + 1024 + s1);
        a2 = *(const f16x8*)(Ac + aBase + 2048 + s1);
        a3 = *(const f16x8*)(Ac + aBase + 3072 + s1);
        gl_lds16(bSrc[0] + ko, Bn + bDst[0]);
        gl_lds16(bSrc[1] + ko, Bn + bDst[1]);
        __builtin_amdgcn_s_setprio(1);
        MFMA4(0, a0) MFMA4(1, a1) MFMA4(2, a2) MFMA4(3, a3)
        __builtin_amdgcn_s_setprio(0);
        a0 = *(const f16x8*)(Ac + aBase + 4096 + s1);
        a1 = *(const f16x8*)(Ac + aBase + 5120 + s1);
        a2 = *(const f16x8*)(Ac + aBase + 6144 + s1);
        a3 = *(const f16x8*)(Ac + aBase + 7168 + s1);
        gl_lds16(bSrc[2] + ko, Bn + bDst[2]);
        gl_lds16(bSrc[3] + ko, Bn + bDst[3]);
        __builtin_amdgcn_s_setprio(1);
        MFMA4(4, a0) MFMA4(5, a1) MFMA4(6, a2) MFMA4(7, a3)
        __builtin_amdgcn_s_setprio(0);
        asm volatile("s_waitcnt vmcnt(0)" ::: "memory");
        __builtin_amdgcn_s_barrier();
    }

    int rq4 = hi << 2;
#pragma unroll
    for (int mi = 0; mi < 8; ++mi) {
        int row = (wm << 7) + mi * 16 + rq4;
#pragma unroll
        for (int q = 0; q < 4; ++q) {
            int ro = rowOffS[row + q] + n0 + (wn << 6) + fr;
            float wg = wtsS[row + q];
#pragma unroll
            for (int ni = 0; ni < 4; ++ni) {
                atomicAdd(&out[ro + ni * 16], acc[mi][ni][q] * wg);
            }
        }
    }
}

// ------------------------------------------------- normalize + loss ---------
__global__ void k_final(float* __restrict__ out, const float* __restrict__ counts,
                        const float* __restrict__ scal, float* __restrict__ loss_out) {
    size_t gid = (size_t)blockIdx.x * 256 + threadIdx.x;
    int tok = (int)(gid >> 8);
    float c = fmaxf(counts[tok], 1.0f);
    float4* o4 = (float4*)out;
    float4 v = o4[gid];
    v.x /= c; v.y /= c; v.z /= c; v.w /= c;
    o4[gid] = v;
    if (gid == 0) {
        float z = scal[0] / (float)(NTOK * E_);
        float aux = 0.f;
#pragma unroll
        for (int e = 0; e < E_; ++e) {
            float u = scal[1 + e] / (float)NTOK - 0.125f;
            aux += u * u;
        }
        loss_out[0] = 0.01f * aux + 0.001f * z;
    }
}

// ----------------------------------------------------------------------------
extern "C" void kernel_launch(void* const* d_in, const int* in_sizes, int n_in,
                              void* d_out, int out_size, void* d_ws, size_t ws_size,
                              hipStream_t stream) {
    const float* x  = (const float*)d_in[0];
    const float* rw = (const float*)d_in[1];
    const float* w1 = (const float*)d_in[2];
    const float* w2 = (const float*)d_in[3];
    float* out = (float*)d_out;
    char* ws = (char*)d_ws;

    float* logits = (float*)(ws + OFF_LOGITS);
    int*   tki    = (int*)(ws + OFF_TOPKI);
    float* tkw    = (float*)(ws + OFF_TOPKW);
    float* counts = (float*)(ws + OFF_COUNTS);
    float* scal   = (float*)(ws + OFF_SCAL);
    f16*   xh     = (f16*)(ws + OFF_XH);
    f16*   wt     = (f16*)(ws + OFF_WT);     // w1t, then reused as w2t
    f16*   mid    = (f16*)(ws + OFF_MID);

    hipMemsetAsync(ws + OFF_COUNTS, 0, 64u * 1024u + 64u, stream);
    hipMemsetAsync(d_out, 0, (size_t)out_size * sizeof(float), stream);

    k_cvt_x<<<NTOK * H_ / 8 / 256, 256, 0, stream>>>(x, xh);
    k_transpose<H_, I_><<<dim3(I_ / 64, H_ / 64, E_), 256, 0, stream>>>(w1, wt);
    k_router<<<NTOK / 4, 256, 0, stream>>>(x, rw, logits, scal);
    k_topk<<<NBE, 1024, 0, stream>>>(logits, tki, tkw, counts);
    k_gemm1<<<1280, 512, 0, stream>>>(xh, wt, tki, mid);
    // reuse WT region for w2t (stream-ordered after gemm1 finished reading w1t)
    k_transpose<I_, H_><<<dim3(H_ / 64, I_ / 64, E_), 256, 0, stream>>>(w2, wt);
    k_gemm2<<<1280, 512, 0, stream>>>(mid, wt, tki, tkw, out);
    k_final<<<(NTOK * H_ / 4) / 256, 256, 0, stream>>>(out, counts, scal,
                                                       out + (size_t)NTOK * H_);
}